// Round 4
// baseline (1046.332 us; speedup 1.0000x reference)
//
#include <hip/hip_runtime.h>
#include <math.h>

typedef _Float16 f16;
typedef _Float16 f16x8 __attribute__((ext_vector_type(8)));
typedef float f32x4 __attribute__((ext_vector_type(4)));

#define LDIM 128
#define HOUT 256

__device__ __forceinline__ float tanh_fast(float x) {
    float a = fabsf(x);
    float e = __expf(-2.0f * a);
    float r = (1.0f - e) / (1.0f + e);
    return copysignf(r, x);
}

// wt_i: [k][h][c] f16  <- W_i[h][c][k]
// wt2h: packed A-frag layout for the persistent kernel:
//   wt2h[(((s*8+kk)*16 + h16)*64 + lane)*8 + j] = W_h[h16*16+(lane&15)][kk*32+(lane>>4)*8+j][s]
__global__ void prep_w(const float* __restrict__ wi, f16* __restrict__ wti,
                       const float* __restrict__ wh, f16* __restrict__ wt2h)
{
    int idx = blockIdx.x * 256 + threadIdx.x;
    const int ni = 3 * HOUT * 128;            // 98304
    if (idx < ni) {
        int k = idx / (HOUT * 128);
        int r = idx - k * (HOUT * 128);
        int h = r >> 7, c = r & 127;
        wti[idx] = (f16)wi[(h * 128 + c) * 3 + k];
    } else {
        int e = idx - ni;
        if (e >= 3 * HOUT * 256) return;      // 196608
        int j    = e & 7;
        int lane = (e >> 3) & 63;
        int h16  = (e >> 9) & 15;
        int kk   = (e >> 13) & 7;
        int s    = e >> 16;
        int hh = h16 * 16 + (lane & 15);
        int c  = kk * 32 + (lane >> 4) * 8 + j;
        wt2h[e] = (f16)wh[(hh * 256 + c) * 3 + s];
    }
}

// ---------------- Phase 1: Z[n] = conv_i(x[n]), all n in parallel ----------------
// XCD-clustered decode: n = bid & 1023, sub = bid >> 10  (all 8 subs of n share bid%8 -> same XCD L2)
__global__ __launch_bounds__(256, 4)
void conv_i_all(const float* __restrict__ x, const f16* __restrict__ wt,
                float* __restrict__ out)
{
    __shared__ __align__(16) char smem[33792];
    const int tid = threadIdx.x;
    const int lane = tid & 63, wid = tid >> 6;
    const int wh = wid >> 1, wl = wid & 1;
    const int n   = blockIdx.x & 1023;
    const int sub = blockIdx.x >> 10;
    const int h0  = (sub >> 1) * 64;
    const int Lb  = (sub & 1) * 64;
    const int l16 = lane & 15, g = lane >> 4;

    const float* actn = x + (long)n * (128 * LDIM);

    {
        const int c4 = tid >> 4;
        const int rb = tid & 15;
        const int lg = Lb + rb * 4;
        f32x4 v[8];
#pragma unroll
        for (int ci = 0; ci < 8; ++ci)
            v[ci] = *(const f32x4*)(actn + (c4 * 8 + ci) * LDIM + lg);
#pragma unroll
        for (int i = 0; i < 4; ++i) {
            int r = rb * 4 + i + 1;
            f16x8 hi, lo;
#pragma unroll
            for (int ci = 0; ci < 8; ++ci) {
                float xx = v[ci][i];
                f16 h = (f16)xx;
                hi[ci] = h;
                lo[ci] = (f16)(xx - (float)h);
            }
            int base = r * 256 + ((c4 ^ (r & 7)) << 4);
            *(f16x8*)(smem + base) = hi;
            *(f16x8*)(smem + 16896 + base) = lo;
        }
        int cl = tid & 127, e = tid >> 7;
        int r = e ? 65 : 0;
        int lg2 = Lb + r - 1;
        float xx = ((unsigned)lg2 < 128u) ? actn[cl * LDIM + lg2] : 0.f;
        f16 h = (f16)xx;
        f16 lo = (f16)(xx - (float)h);
        int off = r * 256 + ((((cl >> 3) ^ (r & 7)) << 4)) + (cl & 7) * 2;
        *(f16*)(smem + off) = h;
        *(f16*)(smem + 16896 + off) = lo;
    }
    __syncthreads();

    f32x4 acc[2][2] = {};
#pragma unroll
    for (int kk = 0; kk < 4; ++kk) {
        f16x8 afr[3][2];
#pragma unroll
        for (int s = 0; s < 3; ++s)
#pragma unroll
            for (int hf = 0; hf < 2; ++hf) {
                int hh = h0 + wh * 32 + hf * 16 + l16;
                afr[s][hf] = *(const f16x8*)(wt + ((s * HOUT + hh) << 7) + kk * 32 + g * 8);
            }
#pragma unroll
        for (int s = 0; s < 3; ++s) {
            f16x8 bfr[2][2];
#pragma unroll
            for (int lf = 0; lf < 2; ++lf) {
                int r = wl * 32 + lf * 16 + l16 + s;
                int base = r * 256 + ((((kk * 4 + g) ^ (r & 7)) << 4));
                bfr[lf][0] = *(const f16x8*)(smem + base);
                bfr[lf][1] = *(const f16x8*)(smem + 16896 + base);
            }
#pragma unroll
            for (int hf = 0; hf < 2; ++hf)
#pragma unroll
                for (int lf = 0; lf < 2; ++lf) {
                    acc[hf][lf] = __builtin_amdgcn_mfma_f32_16x16x32_f16(
                        afr[s][hf], bfr[lf][0], acc[hf][lf], 0, 0, 0);
                    acc[hf][lf] = __builtin_amdgcn_mfma_f32_16x16x32_f16(
                        afr[s][hf], bfr[lf][1], acc[hf][lf], 0, 0, 0);
                }
        }
    }

    float* outn = out + (long)n * (HOUT * LDIM);
#pragma unroll
    for (int hf = 0; hf < 2; ++hf)
#pragma unroll
        for (int lf = 0; lf < 2; ++lf)
#pragma unroll
            for (int vv = 0; vv < 4; ++vv) {
                int hh = h0 + wh * 32 + hf * 16 + g * 4 + vv;
                int ll = Lb + wl * 32 + lf * 16 + l16;
                outn[hh * LDIM + ll] = acc[hf][lf][vv];
            }
}

// ---------------- Phase 2: persistent recurrence kernel ----------------
// grid 256, 1 block/CU. bid: b = bid&15 (b-group shares XCD), sub = bid>>4:
// h0 = (sub>>2)*64, Lb = (sub&3)*32. 4 waves, wave tile 32h x 16l.
// Weights: 48 f16x8 A-frags in registers (loaded once). Act staging in LDS (hi/lo).
// Cross-block sync per b: counter in ws; release fence + atomicAdd, acquire spin.
__global__ __launch_bounds__(256, 1)
void rnn_persist(const f16* __restrict__ wt2, float* __restrict__ out,
                 unsigned int* __restrict__ cnt)
{
    __shared__ __align__(16) char smem[34816];
    const int tid = threadIdx.x;
    const int lane = tid & 63, wid = tid >> 6;
    const int wh = wid >> 1, wl = wid & 1;
    const int b   = blockIdx.x & 15;
    const int sub = blockIdx.x >> 4;
    const int h0  = (sub >> 2) * 64;
    const int Lb  = (sub & 3) * 32;
    const int l16 = lane & 15, g = lane >> 4;
    const long HL = (long)HOUT * LDIM;
    float* outb = out + (long)b * (64 * HL);
    unsigned int* cb = cnt + b * 64;   // 256 B apart

    // ---- A-frags (weights) into registers, once
    f16x8 afr[3][8][2];
#pragma unroll
    for (int s = 0; s < 3; ++s)
#pragma unroll
        for (int kk = 0; kk < 8; ++kk)
#pragma unroll
            for (int hf = 0; hf < 2; ++hf) {
                int h16 = (h0 >> 4) + wh * 2 + hf;
                afr[s][kk][hf] = *(const f16x8*)(wt2 +
                    ((((s * 8 + kk) * 16 + h16) * 64 + lane) << 3));
            }

    // ---- t = 0: h_0 = tanh(Z_0), in place
#pragma unroll
    for (int hf = 0; hf < 2; ++hf)
#pragma unroll
        for (int vv = 0; vv < 4; ++vv) {
            int hh = h0 + wh * 32 + hf * 16 + g * 4 + vv;
            int ll = Lb + wl * 16 + l16;
            long idx = (long)hh * LDIM + ll;
            outb[idx] = tanh_fast(outb[idx]);
        }

    for (int t = 1; t < 64; ++t) {
        float* outt = outb + (long)t * HL;
        const float* prev = outb + (long)(t - 1) * HL;

        // prefetch Z_t (independent of the recurrence)
        float zreg[2][4];
#pragma unroll
        for (int hf = 0; hf < 2; ++hf)
#pragma unroll
            for (int vv = 0; vv < 4; ++vv) {
                int hh = h0 + wh * 32 + hf * 16 + g * 4 + vv;
                int ll = Lb + wl * 16 + l16;
                zreg[hf][vv] = outt[(long)hh * LDIM + ll];
            }

        __syncthreads();   // all waves' t-1 stores drained (barrier implies vmcnt(0))
        if (tid == 0) {
            __threadfence();               // agent release: L2 writeback
            atomicAdd(cb, 1u);             // arrive: finished t-1
            unsigned int target = 16u * (unsigned)t;
            while (__hip_atomic_load(cb, __ATOMIC_ACQUIRE,
                                     __HIP_MEMORY_SCOPE_AGENT) < target)
                __builtin_amdgcn_s_sleep(2);
        }
        __syncthreads();   // block proceeds only after group reached t-1 done

        // ---- stage h_{t-1}[256c][Lb-1..Lb+32] -> LDS hi/lo, swizzled
        {
            const int cq = tid >> 3;   // 32 c-groups of 8
            const int lq = tid & 7;    // 8 l-quads of 4
            const int lg = Lb + lq * 4;
            f32x4 v[8];
#pragma unroll
            for (int ci = 0; ci < 8; ++ci)
                v[ci] = *(const f32x4*)(prev + (cq * 8 + ci) * LDIM + lg);
#pragma unroll
            for (int i = 0; i < 4; ++i) {
                int r = lq * 4 + i + 1;
                f16x8 hi, lo;
#pragma unroll
                for (int ci = 0; ci < 8; ++ci) {
                    float xx = v[ci][i];
                    f16 h = (f16)xx;
                    hi[ci] = h;
                    lo[ci] = (f16)(xx - (float)h);
                }
                int base = r * 512 + ((cq ^ (r & 7)) << 4);
                *(f16x8*)(smem + base) = hi;
                *(f16x8*)(smem + 17408 + base) = lo;
            }
            const int cl = tid;
#pragma unroll
            for (int e = 0; e < 2; ++e) {
                int r = e ? 33 : 0;
                int lg2 = Lb + r - 1;
                float xx = ((unsigned)lg2 < 128u) ? prev[cl * LDIM + lg2] : 0.f;
                f16 h = (f16)xx;
                f16 lo = (f16)(xx - (float)h);
                int off = r * 512 + ((((cl >> 3) ^ (r & 7)) << 4)) + (cl & 7) * 2;
                *(f16*)(smem + off) = h;
                *(f16*)(smem + 17408 + off) = lo;
            }
        }
        __syncthreads();

        // ---- compute: acc[hf] += sum over 24 ksteps x 2 planes
        f32x4 acc[2] = {};
#pragma unroll
        for (int kk = 0; kk < 8; ++kk)
#pragma unroll
            for (int s = 0; s < 3; ++s) {
                int r = wl * 16 + l16 + s;
                int base = r * 512 + ((((kk * 4 + g) ^ (r & 7)) << 4));
                f16x8 b0 = *(const f16x8*)(smem + base);
                f16x8 b1 = *(const f16x8*)(smem + 17408 + base);
#pragma unroll
                for (int hf = 0; hf < 2; ++hf) {
                    acc[hf] = __builtin_amdgcn_mfma_f32_16x16x32_f16(
                        afr[s][kk][hf], b0, acc[hf], 0, 0, 0);
                    acc[hf] = __builtin_amdgcn_mfma_f32_16x16x32_f16(
                        afr[s][kk][hf], b1, acc[hf], 0, 0, 0);
                }
            }

        // ---- epilogue: h_t = tanh(conv + Z_t), overwrite Z_t
#pragma unroll
        for (int hf = 0; hf < 2; ++hf)
#pragma unroll
            for (int vv = 0; vv < 4; ++vv) {
                int hh = h0 + wh * 32 + hf * 16 + g * 4 + vv;
                int ll = Lb + wl * 16 + l16;
                outt[(long)hh * LDIM + ll] = tanh_fast(acc[hf][vv] + zreg[hf][vv]);
            }
    }
}

extern "C" void kernel_launch(void* const* d_in, const int* in_sizes, int n_in,
                              void* d_out, int out_size, void* d_ws, size_t ws_size,
                              hipStream_t stream)
{
    const float* x   = (const float*)d_in[0];   // [16][64][128][128]
    const float* W_i = (const float*)d_in[1];   // [256][128][3]
    const float* W_h = (const float*)d_in[2];   // [256][256][3]
    float* out = (float*)d_out;                 // [16][64][256][128]

    f16* wt_i  = (f16*)d_ws;                                   // 196608 B
    f16* wt2_h = (f16*)((char*)d_ws + 196608);                 // 393216 B
    unsigned int* cnt = (unsigned int*)((char*)d_ws + 589824); // 4096 B

    prep_w<<<1152, 256, 0, stream>>>(W_i, wt_i, W_h, wt2_h);
    hipMemsetAsync(cnt, 0, 4096, stream);

    // Phase 1: Z = conv_i(x) for all (b,t), XCD-clustered
    conv_i_all<<<8192, 256, 0, stream>>>(x, wt_i, out);

    // Phase 2: persistent recurrence, 1 block/CU, 16 blocks per batch element
    rnn_persist<<<256, 256, 0, stream>>>(wt2_h, out, cnt);
}

// Round 5
// 432.959 us; speedup vs baseline: 2.4167x; 2.4167x over previous
//
#include <hip/hip_runtime.h>
#include <math.h>

typedef _Float16 f16;
typedef _Float16 f16x8 __attribute__((ext_vector_type(8)));
typedef float f32x4 __attribute__((ext_vector_type(4)));
typedef unsigned long long u64;

#define LDIM 128
#define HOUT 256

__device__ __forceinline__ float tanh_fast(float x) {
    float a = fabsf(x);
    float e = __expf(-2.0f * a);
    float r = (1.0f - e) / (1.0f + e);
    return copysignf(r, x);
}

// LLC-coherent (agent-scope, relaxed) accessors: emit sc1 loads/stores, no L2 inv/wb
__device__ __forceinline__ void  st_agent(float* p, float v) {
    __hip_atomic_store(p, v, __ATOMIC_RELAXED, __HIP_MEMORY_SCOPE_AGENT);
}
__device__ __forceinline__ float ld_agent(const float* p) {
    return __hip_atomic_load(p, __ATOMIC_RELAXED, __HIP_MEMORY_SCOPE_AGENT);
}
__device__ __forceinline__ u64   ld_agent64(const u64* p) {
    return __hip_atomic_load(p, __ATOMIC_RELAXED, __HIP_MEMORY_SCOPE_AGENT);
}

// wt_i: [k][h][c] f16  <- W_i[h][c][k]
// wt2h: packed A-frags: wt2h[(((s*8+kk)*16+h16)*64+lane)*8+j] = W_h[h16*16+(lane&15)][kk*32+(lane>>4)*8+j][s]
__global__ void prep_w(const float* __restrict__ wi, f16* __restrict__ wti,
                       const float* __restrict__ wh, f16* __restrict__ wt2h)
{
    int idx = blockIdx.x * 256 + threadIdx.x;
    const int ni = 3 * HOUT * 128;
    if (idx < ni) {
        int k = idx / (HOUT * 128);
        int r = idx - k * (HOUT * 128);
        int h = r >> 7, c = r & 127;
        wti[idx] = (f16)wi[(h * 128 + c) * 3 + k];
    } else {
        int e = idx - ni;
        if (e >= 3 * HOUT * 256) return;
        int j    = e & 7;
        int lane = (e >> 3) & 63;
        int h16  = (e >> 9) & 15;
        int kk   = (e >> 13) & 7;
        int s    = e >> 16;
        int hh = h16 * 16 + (lane & 15);
        int c  = kk * 32 + (lane >> 4) * 8 + j;
        wt2h[e] = (f16)wh[(hh * 256 + c) * 3 + s];
    }
}

// ---------------- Phase 1: Z[n] = conv_i(x[n]), all n in parallel (XCD-clustered) ----------------
__global__ __launch_bounds__(256, 4)
void conv_i_all(const float* __restrict__ x, const f16* __restrict__ wt,
                float* __restrict__ out)
{
    __shared__ __align__(16) char smem[33792];
    const int tid = threadIdx.x;
    const int lane = tid & 63, wid = tid >> 6;
    const int wh = wid >> 1, wl = wid & 1;
    const int n   = blockIdx.x & 1023;
    const int sub = blockIdx.x >> 10;
    const int h0  = (sub >> 1) * 64;
    const int Lb  = (sub & 1) * 64;
    const int l16 = lane & 15, g = lane >> 4;

    const float* actn = x + (long)n * (128 * LDIM);

    {
        const int c4 = tid >> 4;
        const int rb = tid & 15;
        const int lg = Lb + rb * 4;
        f32x4 v[8];
#pragma unroll
        for (int ci = 0; ci < 8; ++ci)
            v[ci] = *(const f32x4*)(actn + (c4 * 8 + ci) * LDIM + lg);
#pragma unroll
        for (int i = 0; i < 4; ++i) {
            int r = rb * 4 + i + 1;
            f16x8 hi, lo;
#pragma unroll
            for (int ci = 0; ci < 8; ++ci) {
                float xx = v[ci][i];
                f16 h = (f16)xx;
                hi[ci] = h;
                lo[ci] = (f16)(xx - (float)h);
            }
            int base = r * 256 + ((c4 ^ (r & 7)) << 4);
            *(f16x8*)(smem + base) = hi;
            *(f16x8*)(smem + 16896 + base) = lo;
        }
        int cl = tid & 127, e = tid >> 7;
        int r = e ? 65 : 0;
        int lg2 = Lb + r - 1;
        float xx = ((unsigned)lg2 < 128u) ? actn[cl * LDIM + lg2] : 0.f;
        f16 h = (f16)xx;
        f16 lo = (f16)(xx - (float)h);
        int off = r * 256 + ((((cl >> 3) ^ (r & 7)) << 4)) + (cl & 7) * 2;
        *(f16*)(smem + off) = h;
        *(f16*)(smem + 16896 + off) = lo;
    }
    __syncthreads();

    f32x4 acc[2][2] = {};
#pragma unroll
    for (int kk = 0; kk < 4; ++kk) {
        f16x8 afr[3][2];
#pragma unroll
        for (int s = 0; s < 3; ++s)
#pragma unroll
            for (int hf = 0; hf < 2; ++hf) {
                int hh = h0 + wh * 32 + hf * 16 + l16;
                afr[s][hf] = *(const f16x8*)(wt + ((s * HOUT + hh) << 7) + kk * 32 + g * 8);
            }
#pragma unroll
        for (int s = 0; s < 3; ++s) {
            f16x8 bfr[2][2];
#pragma unroll
            for (int lf = 0; lf < 2; ++lf) {
                int r = wl * 32 + lf * 16 + l16 + s;
                int base = r * 256 + ((((kk * 4 + g) ^ (r & 7)) << 4));
                bfr[lf][0] = *(const f16x8*)(smem + base);
                bfr[lf][1] = *(const f16x8*)(smem + 16896 + base);
            }
#pragma unroll
            for (int hf = 0; hf < 2; ++hf)
#pragma unroll
                for (int lf = 0; lf < 2; ++lf) {
                    acc[hf][lf] = __builtin_amdgcn_mfma_f32_16x16x32_f16(
                        afr[s][hf], bfr[lf][0], acc[hf][lf], 0, 0, 0);
                    acc[hf][lf] = __builtin_amdgcn_mfma_f32_16x16x32_f16(
                        afr[s][hf], bfr[lf][1], acc[hf][lf], 0, 0, 0);
                }
        }
    }

    float* outn = out + (long)n * (HOUT * LDIM);
#pragma unroll
    for (int hf = 0; hf < 2; ++hf)
#pragma unroll
        for (int lf = 0; lf < 2; ++lf)
#pragma unroll
            for (int vv = 0; vv < 4; ++vv) {
                int hh = h0 + wh * 32 + hf * 16 + g * 4 + vv;
                int ll = Lb + wl * 32 + lf * 16 + l16;
                outn[hh * LDIM + ll] = acc[hf][lf][vv];
            }
}

// ---------------- Phase 2: persistent recurrence, LLC-coherent handoff ----------------
// grid 256: b = bid&15, sub = bid>>4 -> h0 = (sub>>2)*64, Lb = (sub&3)*32.
// All cross-block data (h stores, h staging loads, counters) via relaxed agent-scope
// (sc1, Infinity-Cache-coherent) accesses: no threadfence / cache maintenance.
__global__ __launch_bounds__(256, 1)
void rnn_persist(const f16* __restrict__ wt2, float* __restrict__ out,
                 unsigned int* __restrict__ cnt)
{
    __shared__ __align__(16) char smem[34816];
    const int tid = threadIdx.x;
    const int lane = tid & 63, wid = tid >> 6;
    const int wh = wid >> 1, wl = wid & 1;
    const int b   = blockIdx.x & 15;
    const int sub = blockIdx.x >> 4;
    const int h0  = (sub >> 2) * 64;
    const int Lb  = (sub & 3) * 32;
    const int l16 = lane & 15, g = lane >> 4;
    const long HL = (long)HOUT * LDIM;
    float* outb = out + (long)b * (64 * HL);
    unsigned int* cb = cnt + b * 64;   // 256 B apart

    // ---- weights into registers, once
    f16x8 afr[3][8][2];
#pragma unroll
    for (int s = 0; s < 3; ++s)
#pragma unroll
        for (int kk = 0; kk < 8; ++kk)
#pragma unroll
            for (int hf = 0; hf < 2; ++hf) {
                int h16 = (h0 >> 4) + wh * 2 + hf;
                afr[s][kk][hf] = *(const f16x8*)(wt2 +
                    ((((s * 8 + kk) * 16 + h16) * 64 + lane) << 3));
            }

    // ---- t = 0: h_0 = tanh(Z_0), in place, LLC-visible stores
#pragma unroll
    for (int hf = 0; hf < 2; ++hf)
#pragma unroll
        for (int vv = 0; vv < 4; ++vv) {
            int hh = h0 + wh * 32 + hf * 16 + g * 4 + vv;
            int ll = Lb + wl * 16 + l16;
            long idx = (long)hh * LDIM + ll;
            st_agent(&outb[idx], tanh_fast(outb[idx]));
        }

    for (int t = 1; t < 64; ++t) {
        float* outt = outb + (long)t * HL;
        const float* prev = outb + (long)(t - 1) * HL;

        // prefetch Z_t (own tile; lines only ever touched by this block's normal loads)
        float zreg[2][4];
#pragma unroll
        for (int hf = 0; hf < 2; ++hf)
#pragma unroll
            for (int vv = 0; vv < 4; ++vv) {
                int hh = h0 + wh * 32 + hf * 16 + g * 4 + vv;
                int ll = Lb + wl * 16 + l16;
                zreg[hf][vv] = outt[(long)hh * LDIM + ll];
            }

        __syncthreads();   // every wave drains vmcnt -> all sc1 h-stores ack'd at LLC
        if (tid == 0) {
            __hip_atomic_fetch_add(cb, 1u, __ATOMIC_RELAXED, __HIP_MEMORY_SCOPE_AGENT);
            unsigned int target = 16u * (unsigned)t;
            while (__hip_atomic_load(cb, __ATOMIC_RELAXED,
                                     __HIP_MEMORY_SCOPE_AGENT) < target)
                __builtin_amdgcn_s_sleep(1);
        }
        __syncthreads();
        asm volatile("" ::: "memory");   // keep staging loads below the sync

        // ---- stage h_{t-1}[256c][Lb-1..Lb+32] -> LDS hi/lo, swizzled; sc1 u64 loads
        {
            const int cq = tid >> 3;   // 32 c-groups of 8
            const int lq = tid & 7;    // 8 l-quads of 4
            const int lg = Lb + lq * 4;
            f32x4 v[8];
#pragma unroll
            for (int ci = 0; ci < 8; ++ci) {
                const u64* p = (const u64*)(prev + (cq * 8 + ci) * LDIM + lg);
                u64 a = ld_agent64(p);
                u64 bq = ld_agent64(p + 1);
                v[ci][0] = __uint_as_float((unsigned)a);
                v[ci][1] = __uint_as_float((unsigned)(a >> 32));
                v[ci][2] = __uint_as_float((unsigned)bq);
                v[ci][3] = __uint_as_float((unsigned)(bq >> 32));
            }
#pragma unroll
            for (int i = 0; i < 4; ++i) {
                int r = lq * 4 + i + 1;
                f16x8 hi, lo;
#pragma unroll
                for (int ci = 0; ci < 8; ++ci) {
                    float xx = v[ci][i];
                    f16 h = (f16)xx;
                    hi[ci] = h;
                    lo[ci] = (f16)(xx - (float)h);
                }
                int base = r * 512 + ((cq ^ (r & 7)) << 4);
                *(f16x8*)(smem + base) = hi;
                *(f16x8*)(smem + 17408 + base) = lo;
            }
            const int cl = tid;
#pragma unroll
            for (int e = 0; e < 2; ++e) {
                int r = e ? 33 : 0;
                int lg2 = Lb + r - 1;
                float xx = ((unsigned)lg2 < 128u) ? ld_agent(&prev[cl * LDIM + lg2]) : 0.f;
                f16 h = (f16)xx;
                f16 lo = (f16)(xx - (float)h);
                int off = r * 512 + ((((cl >> 3) ^ (r & 7)) << 4)) + (cl & 7) * 2;
                *(f16*)(smem + off) = h;
                *(f16*)(smem + 17408 + off) = lo;
            }
        }
        __syncthreads();

        // ---- compute
        f32x4 acc[2] = {};
#pragma unroll
        for (int kk = 0; kk < 8; ++kk)
#pragma unroll
            for (int s = 0; s < 3; ++s) {
                int r = wl * 16 + l16 + s;
                int base = r * 512 + ((((kk * 4 + g) ^ (r & 7)) << 4));
                f16x8 b0 = *(const f16x8*)(smem + base);
                f16x8 b1 = *(const f16x8*)(smem + 17408 + base);
#pragma unroll
                for (int hf = 0; hf < 2; ++hf) {
                    acc[hf] = __builtin_amdgcn_mfma_f32_16x16x32_f16(
                        afr[s][kk][hf], b0, acc[hf], 0, 0, 0);
                    acc[hf] = __builtin_amdgcn_mfma_f32_16x16x32_f16(
                        afr[s][kk][hf], b1, acc[hf], 0, 0, 0);
                }
            }

        // ---- epilogue: h_t = tanh(conv + Z_t), LLC-visible stores
#pragma unroll
        for (int hf = 0; hf < 2; ++hf)
#pragma unroll
            for (int vv = 0; vv < 4; ++vv) {
                int hh = h0 + wh * 32 + hf * 16 + g * 4 + vv;
                int ll = Lb + wl * 16 + l16;
                st_agent(&outt[(long)hh * LDIM + ll], tanh_fast(acc[hf][vv] + zreg[hf][vv]));
            }
    }
}

extern "C" void kernel_launch(void* const* d_in, const int* in_sizes, int n_in,
                              void* d_out, int out_size, void* d_ws, size_t ws_size,
                              hipStream_t stream)
{
    const float* x   = (const float*)d_in[0];   // [16][64][128][128]
    const float* W_i = (const float*)d_in[1];   // [256][128][3]
    const float* W_h = (const float*)d_in[2];   // [256][256][3]
    float* out = (float*)d_out;                 // [16][64][256][128]

    f16* wt_i  = (f16*)d_ws;
    f16* wt2_h = (f16*)((char*)d_ws + 196608);
    unsigned int* cnt = (unsigned int*)((char*)d_ws + 589824);

    prep_w<<<1152, 256, 0, stream>>>(W_i, wt_i, W_h, wt2_h);
    hipMemsetAsync(cnt, 0, 4096, stream);

    conv_i_all<<<8192, 256, 0, stream>>>(x, wt_i, out);
    rnn_persist<<<256, 256, 0, stream>>>(wt2_h, out, cnt);
}